// Round 1
// baseline (3363.937 us; speedup 1.0000x reference)
//
#include <hip/hip_runtime.h>
#include <stdint.h>

#define B_    8
#define N_    20000
#define NPTS  (B_*N_)        // 160000
#define G_    10
#define NPIL  100
#define BN_EPS 1e-5f

// ---- workspace layout (bytes) ----
#define OFF_COUNTS   0            // 800 * 4   = 3200
#define OFF_SUMS     3584         // 2400 * 4  = 9600
#define OFF_PIL      13312        // 102400 *4 = 409600
#define ZERO_BYTES   422912       // counts+sums+pil zeroed each call
#define OFF_CENT     422912       // 2400 * 4  = 9600
#define OFF_SEG      432512       // 160000*4  = 640000
#define OFF_H3T      1072512      // 160000*128*2 = 40960000 (bf16, transposed [128][NPTS])
#define OFF_W3T      42032512     // 128*64*4 = 32768
#define WS_NEED      42065280

__device__ __forceinline__ int binidx(float v){
    float t = v + 1.0f;
    t = fminf(fmaxf(t, 0.0f), 1.99f);
    return (int)(t / 0.2f);                 // trunc == floor (t >= 0)
}
__device__ __forceinline__ unsigned short f2bf(float f){
    unsigned u = __float_as_uint(f);
    u += 0x7fffu + ((u >> 16) & 1u);        // round-to-nearest-even
    return (unsigned short)(u >> 16);
}
__device__ __forceinline__ float blo(unsigned u){ return __uint_as_float(u << 16); }
__device__ __forceinline__ float bhi(unsigned u){ return __uint_as_float(u & 0xffff0000u); }

// ---- kernel A: pillar id, counts, centroid sums ----
__global__ __launch_bounds__(256) void kA(const float* __restrict__ x,
                                          int* __restrict__ seg,
                                          int* __restrict__ counts,
                                          float* __restrict__ sums){
    int i = blockIdx.x*256 + threadIdx.x;
    if (i >= NPTS) return;
    float x0 = x[3*i], x1 = x[3*i+1], x2 = x[3*i+2];
    int b  = i / N_;
    // swapped coords p = (Z,Y,X) = (x1, x0, x2); pillar from (Y,X) = (x0, x2)
    int iy = binidx(x0), ix = binidx(x2);
    int s  = iy*G_ + ix;
    seg[i] = s;
    int sb = b*NPIL + s;
    atomicAdd(&counts[sb], 1);
    atomicAdd(&sums[sb*3+0], x1);
    atomicAdd(&sums[sb*3+1], x0);
    atomicAdd(&sums[sb*3+2], x2);
}

// ---- kernel B: centroids + W3 transpose ----
__global__ __launch_bounds__(256) void kB(const int* __restrict__ counts,
                                          const float* __restrict__ sums,
                                          float* __restrict__ cent,
                                          const float* __restrict__ W3,
                                          float* __restrict__ W3T){
    int idx = blockIdx.x*256 + threadIdx.x;
    if (idx < 2400){
        int sb = idx/3;
        cent[idx] = sums[idx] / fmaxf((float)counts[sb], 1.0f);
    } else if (idx < 2400 + 64*128){
        int t = idx - 2400;
        int i = t >> 7, j = t & 127;        // W3[i][j]
        W3T[j*64 + i] = W3[t];
    }
}

// ---- kernel C: per-point MLP 6->32->64->128, store h3 (bf16, transposed), pillar-max ----
__global__ __launch_bounds__(256) void kC(const float* __restrict__ x,
                                          const int* __restrict__ seg,
                                          const float* __restrict__ cent,
                                          const float* __restrict__ W1,
                                          const float* __restrict__ W2,
                                          const float* __restrict__ W3T,
                                          unsigned short* __restrict__ h3T,
                                          int* __restrict__ pil){
    int i = blockIdx.x*256 + threadIdx.x;
    if (i >= NPTS) return;
    int b  = i / N_;
    int sb = b*NPIL + seg[i];
    float p0 = x[3*i+1], p1 = x[3*i], p2 = x[3*i+2];
    float aug[6];
    aug[0]=p0; aug[1]=p1; aug[2]=p2;
    aug[3]=p0-cent[sb*3+0]; aug[4]=p1-cent[sb*3+1]; aug[5]=p2-cent[sb*3+2];

    float h1[32];
    #pragma unroll
    for (int j=0;j<32;j++){
        float a = 0.f;
        #pragma unroll
        for (int k=0;k<6;k++) a += aug[k]*W1[k*32+j];
        h1[j] = fmaxf(a, 0.f);
    }
    float h2[64];
    #pragma unroll
    for (int j=0;j<64;j++){
        float a = 0.f;
        #pragma unroll
        for (int k=0;k<32;k++) a += h1[k]*W2[k*64+j];
        h2[j] = fmaxf(a, 0.f);
    }
    for (int j=0;j<128;j++){
        float a = 0.f;
        const float* w = W3T + j*64;
        #pragma unroll
        for (int k=0;k<64;k++) a += h2[k]*w[k];
        float v = fmaxf(a, 0.f);
        h3T[j*NPTS + i] = f2bf(v);
        if (v > 0.f){
            int vi = __float_as_int(v);
            if (vi > *(volatile int*)&pil[sb*128+j])
                atomicMax(&pil[sb*128+j], vi);
        }
    }
}

// ---- kernel D: [160000,256] @ [256,768], relu, segment-max into out ----
// block: 256 thr; tile: 64 points x 192 cols; A staged bf16 in LDS as [K=256][64]
__global__ __launch_bounds__(256) void kD(const unsigned short* __restrict__ h3T,
                                          const float* __restrict__ pil,
                                          const int* __restrict__ seg,
                                          const float* __restrict__ W4,
                                          float* __restrict__ out){
    __shared__ unsigned short A[256*64];
    __shared__ int sbl[64];
    int tid = threadIdx.x;
    int gi0 = blockIdx.x * 64;
    int jb  = blockIdx.y * 192;

    if (tid < 64){
        int gi = gi0 + tid;
        sbl[tid] = (gi / N_)*NPIL + seg[gi];
    }
    __syncthreads();
    for (int idx = tid; idx < 256*64; idx += 256){
        int k = idx >> 6, p = idx & 63;
        unsigned short v;
        if (k < 128) v = h3T[k*NPTS + gi0 + p];
        else         v = f2bf(pil[sbl[p]*128 + (k-128)]);
        A[idx] = v;
    }
    __syncthreads();

    int tx = tid & 31, ty = tid >> 5;       // tx -> 6 cols, ty -> 8 points
    float acc[8][6];
    #pragma unroll
    for (int p=0;p<8;p++)
        #pragma unroll
        for (int m=0;m<6;m++) acc[p][m] = 0.f;

    const float* wbase = W4 + jb + tx*6;
    for (int k=0;k<256;k++){
        uint4 av = *(const uint4*)&A[k*64 + ty*8];
        float a[8];
        a[0]=blo(av.x); a[1]=bhi(av.x);
        a[2]=blo(av.y); a[3]=bhi(av.y);
        a[4]=blo(av.z); a[5]=bhi(av.z);
        a[6]=blo(av.w); a[7]=bhi(av.w);
        float bb[6];
        const float* w = wbase + k*768;
        #pragma unroll
        for (int m=0;m<6;m++) bb[m] = w[m];
        #pragma unroll
        for (int p=0;p<8;p++)
            #pragma unroll
            for (int m=0;m<6;m++)
                acc[p][m] = fmaf(a[p], bb[m], acc[p][m]);
    }

    #pragma unroll
    for (int p=0;p<8;p++){
        int sb = sbl[ty*8+p];
        float* orow = out + sb*768 + jb + tx*6;
        #pragma unroll
        for (int m=0;m<6;m++){
            float v = acc[p][m];
            if (v > 0.f){
                int vi = __float_as_int(v);
                if (vi > *(volatile int*)(orow + m))
                    atomicMax((int*)(orow + m), vi);
            }
        }
    }
}

// ---- kernel E: per-pillar BatchNorm over (B, 768), in place ----
__global__ __launch_bounds__(256) void kE(float* __restrict__ out,
                                          const float* __restrict__ gamma,
                                          const float* __restrict__ beta){
    int p = blockIdx.x;
    int tid = threadIdx.x;
    float v[B_*3];
    float sum = 0.f, ssq = 0.f;
    #pragma unroll
    for (int b=0;b<B_;b++)
        #pragma unroll
        for (int r=0;r<3;r++){
            float t = out[(b*NPIL + p)*768 + tid + r*256];
            v[b*3+r] = t;
            sum += t; ssq += t*t;
        }
    #pragma unroll
    for (int off=32; off; off>>=1){
        sum += __shfl_xor(sum, off);
        ssq += __shfl_xor(ssq, off);
    }
    __shared__ float ls[8];
    __shared__ float sc[2];
    int lane = tid & 63, w = tid >> 6;
    if (lane == 0){ ls[w] = sum; ls[4+w] = ssq; }
    __syncthreads();
    if (tid == 0){
        float S = ls[0]+ls[1]+ls[2]+ls[3];
        float Q = ls[4]+ls[5]+ls[6]+ls[7];
        float mean = S * (1.0f/6144.0f);
        float var  = Q * (1.0f/6144.0f) - mean*mean;
        float scale = rsqrtf(var + BN_EPS) * gamma[p];
        sc[0] = scale;
        sc[1] = beta[p] - mean*scale;
    }
    __syncthreads();
    float scale = sc[0], shift = sc[1];
    #pragma unroll
    for (int b=0;b<B_;b++)
        #pragma unroll
        for (int r=0;r<3;r++)
            out[(b*NPIL + p)*768 + tid + r*256] = v[b*3+r]*scale + shift;
}

extern "C" void kernel_launch(void* const* d_in, const int* in_sizes, int n_in,
                              void* d_out, int out_size, void* d_ws, size_t ws_size,
                              hipStream_t stream){
    if (ws_size < (size_t)WS_NEED) return;   // clean fail rather than OOB
    const float* x     = (const float*)d_in[0];
    const float* W1    = (const float*)d_in[1];
    const float* W2    = (const float*)d_in[2];
    const float* W3    = (const float*)d_in[3];
    const float* W4    = (const float*)d_in[4];
    const float* gamma = (const float*)d_in[5];
    const float* beta  = (const float*)d_in[6];
    float* out = (float*)d_out;
    char*  ws  = (char*)d_ws;

    int*            counts = (int*)           (ws + OFF_COUNTS);
    float*          sums   = (float*)         (ws + OFF_SUMS);
    float*          pilf   = (float*)         (ws + OFF_PIL);
    float*          cent   = (float*)         (ws + OFF_CENT);
    int*            seg    = (int*)           (ws + OFF_SEG);
    unsigned short* h3T    = (unsigned short*)(ws + OFF_H3T);
    float*          W3T    = (float*)         (ws + OFF_W3T);

    hipMemsetAsync(d_ws, 0, ZERO_BYTES, stream);
    hipMemsetAsync(d_out, 0, (size_t)out_size*sizeof(float), stream);

    kA<<<(NPTS+255)/256, 256, 0, stream>>>(x, seg, counts, sums);
    kB<<<(2400+64*128+255)/256, 256, 0, stream>>>(counts, sums, cent, W3, W3T);
    kC<<<(NPTS+255)/256, 256, 0, stream>>>(x, seg, cent, W1, W2, W3T, h3T, (int*)pilf);
    dim3 gD(NPTS/64, 4);
    kD<<<gD, 256, 0, stream>>>(h3T, pilf, seg, W4, out);
    kE<<<NPIL, 256, 0, stream>>>(out, gamma, beta);
}

// Round 2
// 2689.108 us; speedup vs baseline: 1.2509x; 1.2509x over previous
//
#include <hip/hip_runtime.h>
#include <stdint.h>

#define B_    8
#define N_    20000
#define NPTS  (B_*N_)        // 160000
#define G_    10
#define NPIL  100
#define BN_EPS 1e-5f

// ---- workspace layout (bytes) ----
#define OFF_COUNTS   0            // 800*4
#define OFF_SUMS     3584         // 2400*4
#define OFF_PIL      13312        // 102400*4
#define ZERO_BYTES   422912
#define OFF_CENT     422912       // 2400*4
#define OFF_SEG      432512       // 160000*4
#define OFF_H3P      1072512      // 160000*128*2 bf16, point-major [NPTS][128]
#define OFF_W4T      42032512     // 768*256*2 bf16, [col][k]
#define OFF_W3T      42425728     // 128*64*4
#define OFF_PILBF    42458496     // 800*128*2 bf16
#define WS_NEED      42663296

typedef __attribute__((ext_vector_type(8))) short bf16x8;
typedef __attribute__((ext_vector_type(4))) float f32x4;

__device__ __forceinline__ int binidx(float v){
    float t = v + 1.0f;
    t = fminf(fmaxf(t, 0.0f), 1.99f);
    return (int)(t / 0.2f);
}
__device__ __forceinline__ unsigned short f2bf(float f){
    unsigned u = __float_as_uint(f);
    u += 0x7fffu + ((u >> 16) & 1u);
    return (unsigned short)(u >> 16);
}

// ---- kernel A: pillar id, counts, centroid sums ----
__global__ __launch_bounds__(256) void kA(const float* __restrict__ x,
                                          int* __restrict__ seg,
                                          int* __restrict__ counts,
                                          float* __restrict__ sums){
    int i = blockIdx.x*256 + threadIdx.x;
    if (i >= NPTS) return;
    float x0 = x[3*i], x1 = x[3*i+1], x2 = x[3*i+2];
    int b  = i / N_;
    int iy = binidx(x0), ix = binidx(x2);
    int s  = iy*G_ + ix;
    seg[i] = s;
    int sb = b*NPIL + s;
    atomicAdd(&counts[sb], 1);
    atomicAdd(&sums[sb*3+0], x1);
    atomicAdd(&sums[sb*3+1], x0);
    atomicAdd(&sums[sb*3+2], x2);
}

// ---- kernel B: centroids + W3 transpose ----
__global__ __launch_bounds__(256) void kB(const int* __restrict__ counts,
                                          const float* __restrict__ sums,
                                          float* __restrict__ cent,
                                          const float* __restrict__ W3,
                                          float* __restrict__ W3T){
    int idx = blockIdx.x*256 + threadIdx.x;
    if (idx < 2400){
        int sb = idx/3;
        cent[idx] = sums[idx] / fmaxf((float)counts[sb], 1.0f);
    } else if (idx < 2400 + 64*128){
        int t = idx - 2400;
        int i = t >> 7, j = t & 127;
        W3T[j*64 + i] = W3[t];
    }
}

// ---- kernel W: W4 [256][768] fp32 -> W4T [768][256] bf16 ----
__global__ __launch_bounds__(256) void kW(const float* __restrict__ W4,
                                          unsigned short* __restrict__ W4T){
    int idx = blockIdx.x*256 + threadIdx.x;   // idx = k*768 + j (coalesced read)
    if (idx >= 256*768) return;
    int k = idx / 768, j = idx - k*768;
    W4T[j*256 + k] = f2bf(W4[idx]);
}

// ---- kernel C: per-point MLP 6->32->64->128, h3p [NPTS][128] bf16, pillar-max ----
__global__ __launch_bounds__(256) void kC(const float* __restrict__ x,
                                          const int* __restrict__ seg,
                                          const float* __restrict__ cent,
                                          const float* __restrict__ W1,
                                          const float* __restrict__ W2,
                                          const float* __restrict__ W3T,
                                          unsigned short* __restrict__ h3p,
                                          int* __restrict__ pil){
    int i = blockIdx.x*256 + threadIdx.x;
    if (i >= NPTS) return;
    int b  = i / N_;
    int sb = b*NPIL + seg[i];
    float p0 = x[3*i+1], p1 = x[3*i], p2 = x[3*i+2];
    float aug[6];
    aug[0]=p0; aug[1]=p1; aug[2]=p2;
    aug[3]=p0-cent[sb*3+0]; aug[4]=p1-cent[sb*3+1]; aug[5]=p2-cent[sb*3+2];

    float h1[32];
    #pragma unroll
    for (int j=0;j<32;j++){
        float a = 0.f;
        #pragma unroll
        for (int k=0;k<6;k++) a += aug[k]*W1[k*32+j];
        h1[j] = fmaxf(a, 0.f);
    }
    float h2[64];
    #pragma unroll
    for (int j=0;j<64;j++){
        float a = 0.f;
        #pragma unroll
        for (int k=0;k<32;k++) a += h1[k]*W2[k*64+j];
        h2[j] = fmaxf(a, 0.f);
    }
    for (int j0=0;j0<16;j0++){
        unsigned short pack[8] __attribute__((aligned(16)));
        #pragma unroll
        for (int jj=0;jj<8;jj++){
            int j = j0*8+jj;
            float a = 0.f;
            const float* w = W3T + j*64;
            #pragma unroll
            for (int k=0;k<64;k++) a += h2[k]*w[k];
            float v = fmaxf(a, 0.f);
            pack[jj] = f2bf(v);
            if (v > 0.f){
                int vi = __float_as_int(v);
                if (vi > *(volatile int*)&pil[sb*128+j])
                    atomicMax(&pil[sb*128+j], vi);
            }
        }
        *(uint4*)(h3p + (size_t)i*128 + j0*8) = *(const uint4*)pack;
    }
}

// ---- kernel P: pil fp32 -> bf16 ----
__global__ __launch_bounds__(256) void kP(const float* __restrict__ pilf,
                                          unsigned short* __restrict__ pilbf){
    int idx = blockIdx.x*256 + threadIdx.x;
    if (idx >= NPIL*B_*128) return;
    pilbf[idx] = f2bf(pilf[idx]);
}

// ---- kernel D: MFMA GEMM [160000,256]x[256,768] bf16 -> relu -> segmax(atomic) ----
// block 256 thr = 4 waves (2x2), tile 128 pts x 128 cols, full K=256 in LDS.
__global__ __launch_bounds__(256) void kD(const unsigned short* __restrict__ h3p,
                                          const unsigned short* __restrict__ pilbf,
                                          const int* __restrict__ seg,
                                          const unsigned short* __restrict__ W4T,
                                          float* __restrict__ out){
    __shared__ unsigned short Al[128*256];   // 64 KB, row 512B, chunk-swizzled
    __shared__ unsigned short Bl[128*256];   // 64 KB
    __shared__ int sbl[128];
    int tid = threadIdx.x;
    int gi0 = blockIdx.x * 128;
    int n0  = blockIdx.y * 128;

    if (tid < 128){
        int gi = gi0 + tid;
        sbl[tid] = (gi / N_)*NPIL + seg[gi];
    }
    __syncthreads();

    // stage A and B: 128 rows x 32 chunks(16B) each; swizzle: chunk ^= (row&7)
    #pragma unroll
    for (int it=0; it<16; it++){
        int cc  = tid + it*256;
        int row = cc >> 5, ch = cc & 31;
        int chs = ch ^ (row & 7);
        uint4 va;
        if (chs < 16) va = *(const uint4*)(h3p   + (size_t)(gi0+row)*128 + chs*8);
        else          va = *(const uint4*)(pilbf + (size_t)sbl[row]*128 + (chs-16)*8);
        *(uint4*)((char*)Al + cc*16) = va;
        uint4 vb = *(const uint4*)(W4T + (size_t)(n0+row)*256 + chs*8);
        *(uint4*)((char*)Bl + cc*16) = vb;
    }
    __syncthreads();

    int lane = tid & 63, wid = tid >> 6;
    int wm = wid >> 1, wn = wid & 1;
    int l15 = lane & 15, lhi = lane >> 4;

    f32x4 acc[4][4];
    #pragma unroll
    for (int m=0;m<4;m++)
        #pragma unroll
        for (int n=0;n<4;n++)
            acc[m][n] = (f32x4){0.f,0.f,0.f,0.f};

    #pragma unroll
    for (int kk=0; kk<8; kk++){
        bf16x8 af[4], bfr[4];
        #pragma unroll
        for (int f=0; f<4; f++){
            int ra = wm*64 + f*16 + l15;
            af[f]  = *(const bf16x8*)((char*)Al + ra*512 + (((kk*4+lhi) ^ (ra&7))*16));
            int rb = wn*64 + f*16 + l15;
            bfr[f] = *(const bf16x8*)((char*)Bl + rb*512 + (((kk*4+lhi) ^ (rb&7))*16));
        }
        #pragma unroll
        for (int m=0;m<4;m++)
            #pragma unroll
            for (int n=0;n<4;n++)
                acc[m][n] = __builtin_amdgcn_mfma_f32_16x16x32_bf16(af[m], bfr[n], acc[m][n], 0,0,0);
    }

    // epilogue: relu + filtered atomicMax into out[sb][col]
    #pragma unroll
    for (int m=0;m<4;m++){
        #pragma unroll
        for (int r=0;r<4;r++){
            int p  = wm*64 + m*16 + lhi*4 + r;
            int sb = sbl[p];
            float* orow = out + (size_t)sb*768 + n0 + wn*64;
            #pragma unroll
            for (int n=0;n<4;n++){
                float v = acc[m][n][r];
                if (v > 0.f){
                    int vi = __float_as_int(v);
                    int* addr = (int*)(orow + n*16 + l15);
                    if (vi > *(volatile int*)addr) atomicMax(addr, vi);
                }
            }
        }
    }
}

// ---- kernel E: per-pillar BatchNorm over (B, 768), in place ----
__global__ __launch_bounds__(256) void kE(float* __restrict__ out,
                                          const float* __restrict__ gamma,
                                          const float* __restrict__ beta){
    int p = blockIdx.x;
    int tid = threadIdx.x;
    float v[B_*3];
    float sum = 0.f, ssq = 0.f;
    #pragma unroll
    for (int b=0;b<B_;b++)
        #pragma unroll
        for (int r=0;r<3;r++){
            float t = out[(b*NPIL + p)*768 + tid + r*256];
            v[b*3+r] = t;
            sum += t; ssq += t*t;
        }
    #pragma unroll
    for (int off=32; off; off>>=1){
        sum += __shfl_xor(sum, off);
        ssq += __shfl_xor(ssq, off);
    }
    __shared__ float ls[8];
    __shared__ float sc[2];
    int lane = tid & 63, w = tid >> 6;
    if (lane == 0){ ls[w] = sum; ls[4+w] = ssq; }
    __syncthreads();
    if (tid == 0){
        float S = ls[0]+ls[1]+ls[2]+ls[3];
        float Q = ls[4]+ls[5]+ls[6]+ls[7];
        float mean = S * (1.0f/6144.0f);
        float var  = Q * (1.0f/6144.0f) - mean*mean;
        float scale = rsqrtf(var + BN_EPS) * gamma[p];
        sc[0] = scale;
        sc[1] = beta[p] - mean*scale;
    }
    __syncthreads();
    float scale = sc[0], shift = sc[1];
    #pragma unroll
    for (int b=0;b<B_;b++)
        #pragma unroll
        for (int r=0;r<3;r++)
            out[(b*NPIL + p)*768 + tid + r*256] = v[b*3+r]*scale + shift;
}

extern "C" void kernel_launch(void* const* d_in, const int* in_sizes, int n_in,
                              void* d_out, int out_size, void* d_ws, size_t ws_size,
                              hipStream_t stream){
    if (ws_size < (size_t)WS_NEED) return;
    const float* x     = (const float*)d_in[0];
    const float* W1    = (const float*)d_in[1];
    const float* W2    = (const float*)d_in[2];
    const float* W3    = (const float*)d_in[3];
    const float* W4    = (const float*)d_in[4];
    const float* gamma = (const float*)d_in[5];
    const float* beta  = (const float*)d_in[6];
    float* out = (float*)d_out;
    char*  ws  = (char*)d_ws;

    int*            counts = (int*)           (ws + OFF_COUNTS);
    float*          sums   = (float*)         (ws + OFF_SUMS);
    float*          pilf   = (float*)         (ws + OFF_PIL);
    float*          cent   = (float*)         (ws + OFF_CENT);
    int*            seg    = (int*)           (ws + OFF_SEG);
    unsigned short* h3p    = (unsigned short*)(ws + OFF_H3P);
    unsigned short* W4T    = (unsigned short*)(ws + OFF_W4T);
    float*          W3T    = (float*)         (ws + OFF_W3T);
    unsigned short* pilbf  = (unsigned short*)(ws + OFF_PILBF);

    hipMemsetAsync(d_ws, 0, ZERO_BYTES, stream);
    hipMemsetAsync(d_out, 0, (size_t)out_size*sizeof(float), stream);

    kA<<<(NPTS+255)/256, 256, 0, stream>>>(x, seg, counts, sums);
    kB<<<(2400+64*128+255)/256, 256, 0, stream>>>(counts, sums, cent, W3, W3T);
    kW<<<(256*768+255)/256, 256, 0, stream>>>(W4, W4T);
    kC<<<(NPTS+255)/256, 256, 0, stream>>>(x, seg, cent, W1, W2, W3T, h3p, (int*)pilf);
    kP<<<(NPIL*B_*128+255)/256, 256, 0, stream>>>(pilf, pilbf);
    dim3 gD(NPTS/128, 768/128);
    kD<<<gD, 256, 0, stream>>>(h3p, pilbf, seg, W4T, out);
    kE<<<NPIL, 256, 0, stream>>>(out, gamma, beta);
}

// Round 3
// 481.173 us; speedup vs baseline: 6.9911x; 5.5886x over previous
//
#include <hip/hip_runtime.h>
#include <stdint.h>

#define B_    8
#define N_    20000
#define NPTS  (B_*N_)        // 160000
#define G_    10
#define NPIL  100
#define NSB   (B_*NPIL)      // 800 segments
#define BN_EPS 1e-5f

// ---- workspace layout (bytes) ----
#define OFF_COUNTS   0            // 800*4 = 3200
#define OFF_SUMS     3200         // 2400*4 = 9600
#define ZERO_BYTES   12800        // counts+sums zeroed each call
#define OFF_STARTS   12800        // 801*4 -> pad
#define OFF_CURSOR   16064        // 800*4
#define OFF_CENT     19264        // 2400*4
#define OFF_SEG      28864        // 160000*4
#define OFF_W3T      668864       // 128*64*4
#define OFF_W4T      701632       // 768*256*2 bf16 [col][k]
#define OFF_PILBF    1094848      // 800*128*2 bf16
#define OFF_PILW4B   1299648      // 800*768*4 fp32 bias
#define OFF_H3P      3757312      // 160000*128*2 bf16, SORTED rows
#define WS_NEED      44717312

typedef __attribute__((ext_vector_type(8))) short bf16x8;
typedef __attribute__((ext_vector_type(4))) float f32x4;

__device__ __forceinline__ int binidx(float v){
    float t = v + 1.0f;
    t = fminf(fmaxf(t, 0.0f), 1.99f);
    return (int)(t / 0.2f);
}
__device__ __forceinline__ unsigned short f2bf(float f){
    unsigned u = __float_as_uint(f);
    u += 0x7fffu + ((u >> 16) & 1u);
    return (unsigned short)(u >> 16);
}
__device__ __forceinline__ float bf2f(unsigned short s){
    return __uint_as_float(((unsigned)s) << 16);
}

// ---- kA: pillar id, counts, centroid sums ----
__global__ __launch_bounds__(256) void kA(const float* __restrict__ x,
                                          int* __restrict__ seg,
                                          int* __restrict__ counts,
                                          float* __restrict__ sums){
    int i = blockIdx.x*256 + threadIdx.x;
    if (i >= NPTS) return;
    float x0 = x[3*i], x1 = x[3*i+1], x2 = x[3*i+2];
    int b  = i / N_;
    int iy = binidx(x0), ix = binidx(x2);
    int s  = iy*G_ + ix;
    seg[i] = s;
    int sb = b*NPIL + s;
    atomicAdd(&counts[sb], 1);
    atomicAdd(&sums[sb*3+0], x1);
    atomicAdd(&sums[sb*3+1], x0);
    atomicAdd(&sums[sb*3+2], x2);
}

// ---- kScan: exclusive prefix sum over 800 counts (1 block) ----
__global__ __launch_bounds__(1024) void kScan(const int* __restrict__ counts,
                                              int* __restrict__ starts,
                                              int* __restrict__ cursor){
    __shared__ int s[1024];
    int t = threadIdx.x;
    int c = (t < NSB) ? counts[t] : 0;
    s[t] = c;
    __syncthreads();
    for (int off=1; off<1024; off<<=1){
        int v = (t >= off) ? s[t-off] : 0;
        __syncthreads();
        s[t] += v;
        __syncthreads();
    }
    if (t < NSB){ int st = s[t]-c; starts[t] = st; cursor[t] = st; }
    if (t == NSB) starts[NSB] = s[NSB-1];
}

// ---- kB: centroids + W3 transpose + W4 transpose->bf16 ----
__global__ __launch_bounds__(256) void kB(const int* __restrict__ counts,
                                          const float* __restrict__ sums,
                                          float* __restrict__ cent,
                                          const float* __restrict__ W3,
                                          float* __restrict__ W3T,
                                          const float* __restrict__ W4,
                                          unsigned short* __restrict__ W4T){
    int idx = blockIdx.x*256 + threadIdx.x;
    if (idx < 2400){
        cent[idx] = sums[idx] / fmaxf((float)counts[idx/3], 1.0f);
    } else if (idx < 2400 + 8192){
        int t = idx - 2400;
        int i = t >> 7, j = t & 127;      // W3[i][j]
        W3T[j*64 + i] = W3[t];
    } else if (idx < 2400 + 8192 + 196608){
        int t = idx - 2400 - 8192;        // t = k*768 + j (coalesced read)
        int k = t / 768, j = t - k*768;
        W4T[j*256 + k] = f2bf(W4[t]);
    }
}

// ---- kC: per-point MLP 6->32->64->128, write h3 row at SORTED position ----
__global__ __launch_bounds__(256) void kC(const float* __restrict__ x,
                                          const int* __restrict__ seg,
                                          const float* __restrict__ cent,
                                          const float* __restrict__ W1,
                                          const float* __restrict__ W2,
                                          const float* __restrict__ W3T,
                                          int* __restrict__ cursor,
                                          unsigned short* __restrict__ h3p){
    int i = blockIdx.x*256 + threadIdx.x;
    if (i >= NPTS) return;
    int b  = i / N_;
    int sb = b*NPIL + seg[i];
    int pos = atomicAdd(&cursor[sb], 1);
    float p0 = x[3*i+1], p1 = x[3*i], p2 = x[3*i+2];
    float aug[6];
    aug[0]=p0; aug[1]=p1; aug[2]=p2;
    aug[3]=p0-cent[sb*3+0]; aug[4]=p1-cent[sb*3+1]; aug[5]=p2-cent[sb*3+2];

    float h1[32];
    #pragma unroll
    for (int j=0;j<32;j++){
        float a = 0.f;
        #pragma unroll
        for (int k=0;k<6;k++) a += aug[k]*W1[k*32+j];
        h1[j] = fmaxf(a, 0.f);
    }
    float h2[64];
    #pragma unroll
    for (int j=0;j<64;j++){
        float a = 0.f;
        #pragma unroll
        for (int k=0;k<32;k++) a += h1[k]*W2[k*64+j];
        h2[j] = fmaxf(a, 0.f);
    }
    unsigned short* orow = h3p + (size_t)pos*128;
    for (int j0=0;j0<16;j0++){
        unsigned short pack[8] __attribute__((aligned(16)));
        #pragma unroll
        for (int jj=0;jj<8;jj++){
            int j = j0*8+jj;
            float a = 0.f;
            const float* w = W3T + j*64;
            #pragma unroll
            for (int k=0;k<64;k++) a += h2[k]*w[k];
            pack[jj] = f2bf(fmaxf(a, 0.f));
        }
        *(uint4*)(orow + j0*8) = *(const uint4*)pack;
    }
}

// ---- kM: per-pillar segment-max of h3 (bf16 bits, values >= 0) ----
__global__ __launch_bounds__(128) void kM(const unsigned short* __restrict__ h3p,
                                          const int* __restrict__ starts,
                                          unsigned short* __restrict__ pilbf){
    int sb = blockIdx.x, j = threadIdx.x;
    int s = starts[sb], e = starts[sb+1];
    unsigned short m = 0;
    for (int p=s; p<e; p++){
        unsigned short v = h3p[(size_t)p*128 + j];
        m = v > m ? v : m;
    }
    pilbf[sb*128 + j] = m;
}

// ---- kPB: per-pillar bias = pil . W4[128:,:]  (768 wide, fp32) ----
__global__ __launch_bounds__(256) void kPB(const unsigned short* __restrict__ pilbf,
                                           const float* __restrict__ W4,
                                           float* __restrict__ pilW4b){
    int sb = blockIdx.x, tid = threadIdx.x;
    __shared__ float pl[128];
    if (tid < 128) pl[tid] = bf2f(pilbf[sb*128 + tid]);
    __syncthreads();
    #pragma unroll
    for (int c=0;c<3;c++){
        int col = tid + c*256;
        float a = 0.f;
        #pragma unroll 8
        for (int k=0;k<128;k++) a = fmaf(pl[k], W4[(size_t)(128+k)*768 + col], a);
        pilW4b[(size_t)sb*768 + col] = a;
    }
}

// ---- kD: per-(pillar, coltile) MFMA GEMM K=128 + bias + relu + register segmax ----
// block 256 thr = 4 waves (2x2), tile 128 rows x 128 cols; zero atomics.
__global__ __launch_bounds__(256) void kD(const unsigned short* __restrict__ h3p,
                                          const int* __restrict__ starts,
                                          const float* __restrict__ pilW4b,
                                          const unsigned short* __restrict__ W4T,
                                          float* __restrict__ out){
    __shared__ unsigned short Al[128*128];   // 32KB, row 256B, chunk-swizzled
    __shared__ unsigned short Bl[128*128];   // 32KB
    __shared__ float red[2][2][64];
    int sb  = blockIdx.x;
    int n0  = blockIdx.y * 128;
    int tid = threadIdx.x;
    int start = starts[sb];
    int npts  = starts[sb+1] - start;
    if (npts == 0){
        if (tid < 128) out[(size_t)sb*768 + n0 + tid] = 0.f;
        return;
    }
    // stage B once: rows = cols of W4T, 16 chunks of 16B, swizzle ch ^= row&7
    #pragma unroll
    for (int it=0; it<8; it++){
        int cc = tid + it*256;
        int row = cc >> 4, ch = cc & 15;
        int chs = ch ^ (row & 7);
        *(uint4*)((char*)Bl + cc*16) = *(const uint4*)(W4T + (size_t)(n0+row)*256 + chs*8);
    }
    int lane = tid & 63, wid = tid >> 6;
    int wm = wid >> 1, wn = wid & 1;
    int l15 = lane & 15, lhi = lane >> 4;

    float bias[4];
    #pragma unroll
    for (int n=0;n<4;n++) bias[n] = pilW4b[(size_t)sb*768 + n0 + wn*64 + n*16 + l15];

    float mx[4][4][4];
    #pragma unroll
    for (int m=0;m<4;m++)
        #pragma unroll
        for (int n=0;n<4;n++)
            #pragma unroll
            for (int r=0;r<4;r++) mx[m][n][r] = 0.f;

    int nch = (npts + 127) >> 7;
    for (int c=0; c<nch; c++){
        int base = c*128;
        __syncthreads();
        #pragma unroll
        for (int it=0; it<8; it++){
            int cc = tid + it*256;
            int row = cc >> 4, ch = cc & 15;
            int chs = ch ^ (row & 7);
            uint4 v = {0u,0u,0u,0u};
            if (base + row < npts)
                v = *(const uint4*)(h3p + (size_t)(start+base+row)*128 + chs*8);
            *(uint4*)((char*)Al + cc*16) = v;
        }
        __syncthreads();

        f32x4 acc[4][4];
        #pragma unroll
        for (int m=0;m<4;m++)
            #pragma unroll
            for (int n=0;n<4;n++) acc[m][n] = (f32x4){0.f,0.f,0.f,0.f};

        #pragma unroll
        for (int kk=0; kk<4; kk++){
            bf16x8 af[4], bfr[4];
            #pragma unroll
            for (int f=0; f<4; f++){
                int ra = wm*64 + f*16 + l15;
                af[f]  = *(const bf16x8*)((char*)Al + ra*256 + (((kk*4+lhi) ^ (ra&7))*16));
                int rb = wn*64 + f*16 + l15;
                bfr[f] = *(const bf16x8*)((char*)Bl + rb*256 + (((kk*4+lhi) ^ (rb&7))*16));
            }
            #pragma unroll
            for (int m=0;m<4;m++)
                #pragma unroll
                for (int n=0;n<4;n++)
                    acc[m][n] = __builtin_amdgcn_mfma_f32_16x16x32_bf16(af[m], bfr[n], acc[m][n], 0,0,0);
        }

        int nrem = npts - base;
        #pragma unroll
        for (int m=0;m<4;m++)
            #pragma unroll
            for (int r=0;r<4;r++){
                int p = wm*64 + m*16 + lhi*4 + r;
                if (p < nrem){
                    #pragma unroll
                    for (int n=0;n<4;n++)
                        mx[m][n][r] = fmaxf(mx[m][n][r], fmaxf(acc[m][n][r] + bias[n], 0.f));
                }
            }
    }

    // reduce over rows: in-lane (m,r), then lhi via shfl, then wm via LDS
    float red4[4];
    #pragma unroll
    for (int n=0;n<4;n++){
        float v = 0.f;
        #pragma unroll
        for (int m=0;m<4;m++)
            #pragma unroll
            for (int r=0;r<4;r++) v = fmaxf(v, mx[m][n][r]);
        v = fmaxf(v, __shfl_xor(v, 16));
        v = fmaxf(v, __shfl_xor(v, 32));
        red4[n] = v;
    }
    if (lhi == 0){
        #pragma unroll
        for (int n=0;n<4;n++) red[wm][wn][n*16 + l15] = red4[n];
    }
    __syncthreads();
    if (wm == 0){
        float v = fmaxf(red[0][wn][lane], red[1][wn][lane]);
        out[(size_t)sb*768 + n0 + wn*64 + lane] = v;
    }
}

// ---- kE: per-pillar BatchNorm over (B, 768), in place ----
__global__ __launch_bounds__(256) void kE(float* __restrict__ out,
                                          const float* __restrict__ gamma,
                                          const float* __restrict__ beta){
    int p = blockIdx.x;
    int tid = threadIdx.x;
    float v[B_*3];
    float sum = 0.f, ssq = 0.f;
    #pragma unroll
    for (int b=0;b<B_;b++)
        #pragma unroll
        for (int r=0;r<3;r++){
            float t = out[(b*NPIL + p)*768 + tid + r*256];
            v[b*3+r] = t;
            sum += t; ssq += t*t;
        }
    #pragma unroll
    for (int off=32; off; off>>=1){
        sum += __shfl_xor(sum, off);
        ssq += __shfl_xor(ssq, off);
    }
    __shared__ float ls[8];
    __shared__ float sc[2];
    int lane = tid & 63, w = tid >> 6;
    if (lane == 0){ ls[w] = sum; ls[4+w] = ssq; }
    __syncthreads();
    if (tid == 0){
        float S = ls[0]+ls[1]+ls[2]+ls[3];
        float Q = ls[4]+ls[5]+ls[6]+ls[7];
        float mean = S * (1.0f/6144.0f);
        float var  = Q * (1.0f/6144.0f) - mean*mean;
        float scale = rsqrtf(var + BN_EPS) * gamma[p];
        sc[0] = scale;
        sc[1] = beta[p] - mean*scale;
    }
    __syncthreads();
    float scale = sc[0], shift = sc[1];
    #pragma unroll
    for (int b=0;b<B_;b++)
        #pragma unroll
        for (int r=0;r<3;r++)
            out[(b*NPIL + p)*768 + tid + r*256] = v[b*3+r]*scale + shift;
}

extern "C" void kernel_launch(void* const* d_in, const int* in_sizes, int n_in,
                              void* d_out, int out_size, void* d_ws, size_t ws_size,
                              hipStream_t stream){
    if (ws_size < (size_t)WS_NEED) return;
    const float* x     = (const float*)d_in[0];
    const float* W1    = (const float*)d_in[1];
    const float* W2    = (const float*)d_in[2];
    const float* W3    = (const float*)d_in[3];
    const float* W4    = (const float*)d_in[4];
    const float* gamma = (const float*)d_in[5];
    const float* beta  = (const float*)d_in[6];
    float* out = (float*)d_out;
    char*  ws  = (char*)d_ws;

    int*            counts = (int*)           (ws + OFF_COUNTS);
    float*          sums   = (float*)         (ws + OFF_SUMS);
    int*            starts = (int*)           (ws + OFF_STARTS);
    int*            cursor = (int*)           (ws + OFF_CURSOR);
    float*          cent   = (float*)         (ws + OFF_CENT);
    int*            seg    = (int*)           (ws + OFF_SEG);
    float*          W3T    = (float*)         (ws + OFF_W3T);
    unsigned short* W4T    = (unsigned short*)(ws + OFF_W4T);
    unsigned short* pilbf  = (unsigned short*)(ws + OFF_PILBF);
    float*          pilW4b = (float*)         (ws + OFF_PILW4B);
    unsigned short* h3p    = (unsigned short*)(ws + OFF_H3P);

    hipMemsetAsync(d_ws, 0, ZERO_BYTES, stream);

    kA<<<(NPTS+255)/256, 256, 0, stream>>>(x, seg, counts, sums);
    kScan<<<1, 1024, 0, stream>>>(counts, starts, cursor);
    kB<<<(2400+8192+196608+255)/256, 256, 0, stream>>>(counts, sums, cent, W3, W3T, W4, W4T);
    kC<<<(NPTS+255)/256, 256, 0, stream>>>(x, seg, cent, W1, W2, W3T, cursor, h3p);
    kM<<<NSB, 128, 0, stream>>>(h3p, starts, pilbf);
    kPB<<<NSB, 256, 0, stream>>>(pilbf, W4, pilW4b);
    dim3 gD(NSB, 6);
    kD<<<gD, 256, 0, stream>>>(h3p, starts, pilW4b, W4T, out);
    kE<<<NPIL, 256, 0, stream>>>(out, gamma, beta);
}